// Round 5
// baseline (413.315 us; speedup 1.0000x reference)
//
#include <hip/hip_runtime.h>

// LIF activation: x [B=64, T=500, C=1024] fp32, scalars w_input, w_leak.
// Per (b,c): forget=(Vm<1); Vm=relu(wi*x_t + kl*Vm*forget); spike=(Vm>1).
// Output spikes [B, T, C] fp32. Exact-unfused fp32 (absmax=0 in R1-R4).
//
// History:
//  R1 92us: runtime-indexed reg buffer -> scratch spill (WRITE 2x).
//  R2 82us: named reg dbuf -> compiler sank loads (VGPR=52), latency-bound.
//  R3 92us: quad buf + clobbers -> still no reg MLP (VGPR=60).
//  R4 81us: LDS dbuf + global_load_lds + __syncthreads: barrier's
//           s_waitcnt vmcnt(0) drains the whole 25KB burst each chunk;
//           1 wave/SIMD has nothing else to run -> VALUBusy 8%.
//  R5 (this): BARRIER-FREE per-wave pipeline. One wave = 256 channels
//           (4/lane, float4). 32-slot LDS ring of 1KB rows; issue row t+31
//           each iter via global_load_lds(16B); sole sync = inline-asm
//           s_waitcnt vmcnt(31). vmcnt retires in order; row t always has
//           >=31 newer vm-ops (31 stores in tail; 61 in steady state), so
//           vmcnt(31) proves row t landed while ~15 loads (~15KB/CU) stay
//           in flight -- above the ~9KB latency-BW product. No vmcnt(0)
//           anywhere in the loop.

#define LIF_B 64
#define LIF_T 500
#define LIF_C 1024
#define DEPTH 31            // rows in flight
#define RING  32            // LDS ring slots (pow2 > DEPTH)

#define GLOBAL_AS(p) ((__attribute__((address_space(1))) const void*)(uintptr_t)(p))
#define LDS_AS(p)    ((__attribute__((address_space(3))) void*)(uintptr_t)(p))

__global__ __launch_bounds__(64) void lif_kernel(
    const float* __restrict__ x,
    const float* __restrict__ w_input_p,
    const float* __restrict__ w_leak_p,
    float* __restrict__ out) {

  __shared__ float4 ring[RING][64];           // 32 KB: 32 rows x 1 KB

  const int b     = blockIdx.x >> 2;          // 64 b-rows
  const int cbase = (blockIdx.x & 3) << 8;    // 4 groups of 256 channels
  const int lane  = threadIdx.x;              // 0..63; owns channels cbase+4*lane..+3

  const float wi = w_input_p[0];
  const float kl = __fsub_rn(1.0f, w_leak_p[0]);  // 1 - w_leak

  const float* xs = x   + (size_t)b * LIF_T * LIF_C + cbase + lane * 4;
  float*       os = out + (size_t)b * LIF_T * LIF_C + cbase + lane * 4;

  // Issue async copy of row t (1 KB: 64 lanes x 16 B) into ring[t & 31].
  auto stage = [&](int t) {
    __builtin_amdgcn_global_load_lds(GLOBAL_AS(xs + (size_t)t * LIF_C),
                                     LDS_AS(&ring[t & (RING - 1)][0]),
                                     16, 0, 0);
  };

  // Prologue: fill the pipe with rows 0..30.
#pragma unroll
  for (int t = 0; t < DEPTH; ++t) stage(t);
  asm volatile("s_waitcnt vmcnt(30)" ::: "memory");   // row 0 landed

  float V0 = 0.0f, V1 = 0.0f, V2 = 0.0f, V3 = 0.0f;

  for (int t = 0; t < LIF_T; ++t) {
    // Row t has >=31 newer vm-ops for all t>=1 (t=0 via prologue wait):
    // vmcnt(31) => row t landed; ~15 newer loads stay in flight.
    asm volatile("s_waitcnt vmcnt(31)" ::: "memory");

    const float4 xt = ring[t & (RING - 1)][lane];

    float4 sp;
    {
      const float a0 = (V0 < 1.0f) ? __fmul_rn(kl, V0) : 0.0f;
      V0 = fmaxf(__fadd_rn(__fmul_rn(wi, xt.x), a0), 0.0f);
      sp.x = (V0 > 1.0f) ? 1.0f : 0.0f;
      const float a1 = (V1 < 1.0f) ? __fmul_rn(kl, V1) : 0.0f;
      V1 = fmaxf(__fadd_rn(__fmul_rn(wi, xt.y), a1), 0.0f);
      sp.y = (V1 > 1.0f) ? 1.0f : 0.0f;
      const float a2 = (V2 < 1.0f) ? __fmul_rn(kl, V2) : 0.0f;
      V2 = fmaxf(__fadd_rn(__fmul_rn(wi, xt.z), a2), 0.0f);
      sp.z = (V2 > 1.0f) ? 1.0f : 0.0f;
      const float a3 = (V3 < 1.0f) ? __fmul_rn(kl, V3) : 0.0f;
      V3 = fmaxf(__fadd_rn(__fmul_rn(wi, xt.w), a3), 0.0f);
      sp.w = (V3 > 1.0f) ? 1.0f : 0.0f;
    }

    // Refill: row t+31 overwrites slot (t-1)&31, consumed LAST iteration
    // (RING=32 > DEPTH=31), so no read-after-DMA hazard on this row.
    if (t + DEPTH < LIF_T) stage(t + DEPTH);

    *(float4*)(os + (size_t)t * LIF_C) = sp;
  }
}

extern "C" void kernel_launch(void* const* d_in, const int* in_sizes, int n_in,
                              void* d_out, int out_size, void* d_ws, size_t ws_size,
                              hipStream_t stream) {
  const float* x  = (const float*)d_in[0];
  const float* wi = (const float*)d_in[1];
  const float* wl = (const float*)d_in[2];
  float* out = (float*)d_out;

  const int grid = LIF_B * 4;   // 256 blocks x 1 wave = 1 wave/CU
  lif_kernel<<<grid, 64, 0, stream>>>(x, wi, wl, out);
}

// Round 6
// 234.617 us; speedup vs baseline: 1.7617x; 1.7617x over previous
//
#include <hip/hip_runtime.h>

// LIF activation: x [B=64, T=500, C=1024] fp32, scalars w_input, w_leak.
// Per (b,c): forget=(Vm<1); Vm=relu(wi*x_t + kl*Vm*forget); spike=(Vm>1).
// Output spikes [B, T, C] fp32. Exact-unfused fp32 (absmax=0 in R1-R5).
//
// History:
//  R1 92us: runtime-indexed reg buffer -> scratch spill (WRITE 2x).
//  R2 82us: named reg dbuf -> pre-RA scheduler SANK each load to its use
//           (VGPR=52, ~10 in flight) -> latency-bound.
//  R3 92us: asm memory clobbers -> no effect on the scheduler's sinking.
//  R4 81us: LDS dbuf via global_load_lds + barrier -> compiler drains the
//           fresh prefetch at the first aliasing ds_read (LDS-DMA alias
//           tracking is conservative) -> no overlap.
//  R5 259us: barrier-free LDS ring -> same conservative vmcnt(0) before
//           EVERY ds_read -> one full HBM latency per timestep. Conclusion:
//           LDS-DMA staging is unusable when the consumer aliases it.
//  R6 (this): R2 register double-buffer + __builtin_amdgcn_sched_barrier(0)
//           fences between [25-load prefetch] and [25-step compute] phases.
//           Hard fence stops the sinking; waitcnt legalizer then emits its
//           precise per-register vmcnt(N) waits. ~25 loads (100 B/lane) in
//           flight/thread -> 25.6 KB/CU >> ~9 KB latency-BW product.
//           Branch-free rotated loop (clamped prefetch index) keeps the
//           body a single scheduling region.

#define LIF_B 64
#define LIF_T 500
#define LIF_C 1024
#define LIF_U 25                  // timesteps per buffer
#define LIF_NCH (LIF_T / LIF_U)   // 20 chunks, peeled by 2

#define FENCE() __builtin_amdgcn_sched_barrier(0)

#define PREFETCH(buf, kk)                                       \
  do {                                                          \
    const float* xn = xp + (size_t)(kk) * LIF_U * LIF_C;        \
    _Pragma("unroll")                                           \
    for (int u = 0; u < LIF_U; ++u) {                           \
      buf[u] = xn[(size_t)u * LIF_C];                           \
    }                                                           \
  } while (0)

#define COMPUTE(buf, kk)                                        \
  do {                                                          \
    float* on = op + (size_t)(kk) * LIF_U * LIF_C;              \
    _Pragma("unroll")                                           \
    for (int u = 0; u < LIF_U; ++u) {                           \
      const float xt = buf[u];                                  \
      const float acc = (Vm < 1.0f) ? __fmul_rn(kl, Vm) : 0.0f; \
      const float v   = __fadd_rn(__fmul_rn(wi, xt), acc);      \
      Vm = fmaxf(v, 0.0f);                                      \
      on[(size_t)u * LIF_C] = (Vm > 1.0f) ? 1.0f : 0.0f;        \
    }                                                           \
  } while (0)

__global__ __launch_bounds__(256) void lif_kernel(
    const float* __restrict__ x,
    const float* __restrict__ w_input_p,
    const float* __restrict__ w_leak_p,
    float* __restrict__ out) {

  const int tid = blockIdx.x * blockDim.x + threadIdx.x;  // 0 .. 65535
  const int b = tid >> 10;          // / 1024
  const int c = tid & (LIF_C - 1);  // % 1024

  const float wi = w_input_p[0];
  const float kl = __fsub_rn(1.0f, w_leak_p[0]);  // 1 - w_leak

  const float* xp = x   + (size_t)b * LIF_T * LIF_C + c;
  float*       op = out + (size_t)b * LIF_T * LIF_C + c;

  float bufA[LIF_U];
  float bufB[LIF_U];
  float Vm = 0.0f;

  PREFETCH(bufA, 0);
  FENCE();

  for (int k = 0; k < LIF_NCH; k += 2) {
    PREFETCH(bufB, k + 1);          // k+1 <= 19 always
    FENCE();
    COMPUTE(bufA, k);
    FENCE();
    int kn = k + 2;
    kn = (kn > LIF_NCH - 1) ? (LIF_NCH - 1) : kn;  // clamp: last iter reloads 19
    PREFETCH(bufA, kn);
    FENCE();
    COMPUTE(bufB, k + 1);
    FENCE();
  }
}

extern "C" void kernel_launch(void* const* d_in, const int* in_sizes, int n_in,
                              void* d_out, int out_size, void* d_ws, size_t ws_size,
                              hipStream_t stream) {
  const float* x  = (const float*)d_in[0];
  const float* wi = (const float*)d_in[1];
  const float* wl = (const float*)d_in[2];
  float* out = (float*)d_out;

  const int n_threads = LIF_B * LIF_C;  // 65536
  const int block = 256;
  const int grid = n_threads / block;   // 256 blocks, ~1/CU, 4 waves/CU
  lif_kernel<<<grid, block, 0, stream>>>(x, wi, wl, out);
}